// Round 5
// baseline (387.200 us; speedup 1.0000x reference)
//
#include <hip/hip_runtime.h>

typedef unsigned short u16;
typedef unsigned int   u32;
typedef unsigned long long u64;
typedef __attribute__((ext_vector_type(8))) short bf16x8;
typedef __attribute__((ext_vector_type(4))) float f32x4;

#define S_  2048
#define DH  64
#define DM  1024
#define BS  8192
#define CS  0.18033688011112042f   // 0.125 * log2(e)

static __device__ __forceinline__ float bf2f(u16 v){ return __uint_as_float(((u32)v)<<16); }
static __device__ __forceinline__ u16 f2bf(float f){
  u32 x = __float_as_uint(f);
  return (u16)((x + 0x7fffu + ((x>>16)&1u)) >> 16);   // RNE
}
#if __has_builtin(__builtin_amdgcn_cvt_pk_bf16_f32)
static __device__ __forceinline__ u32 pk2(float x, float y){
  typedef __attribute__((ext_vector_type(2))) __bf16 bf2v;
  union { bf2v v; u32 u; } c; c.v = __builtin_amdgcn_cvt_pk_bf16_f32(x, y); return c.u;
}
#else
static __device__ __forceinline__ u32 pk2(float x, float y){
  return (u32)f2bf(x) | ((u32)f2bf(y) << 16);
}
#endif
#if __has_builtin(__builtin_amdgcn_exp2f)
#define EXP2F(x) __builtin_amdgcn_exp2f(x)
#else
#define EXP2F(x) exp2f(x)
#endif

// async global->LDS, 16B/lane; LDS dest = wave-uniform base + lane*16
static __device__ __forceinline__ void dma16(const u16* g, const u16* l){
  __builtin_amdgcn_global_load_lds(
      (const __attribute__((address_space(1))) u32*)(u64)(uintptr_t)g,
      (__attribute__((address_space(3))) u32*)(u32)(u64)(uintptr_t)l, 16, 0, 0);
}

static __device__ __forceinline__ bf16x8 lds_frag(const u16* p){
  union { bf16x8 f; uint2 u[2]; } w;
  w.u[0] = *(const uint2*)(p);
  w.u[1] = *(const uint2*)(p+4);
  return w.f;
}
// 16B-aligned fragment load (single ds_read_b128)
static __device__ __forceinline__ bf16x8 frag16v(const u16* p){
  union { bf16x8 f; uint4 u; } w;
  w.u = *(const uint4*)p;
  return w.f;
}
static __device__ __forceinline__ void stage16_bf(const u16* __restrict__ g, u16* s){
  uint4 a = *(const uint4*)g;
  uint4 b = *(const uint4*)(g+8);
  *(uint2*)(s+0)  = make_uint2(a.x,a.y);
  *(uint2*)(s+4)  = make_uint2(a.z,a.w);
  *(uint2*)(s+8)  = make_uint2(b.x,b.y);
  *(uint2*)(s+12) = make_uint2(b.z,b.w);
}
static __device__ __forceinline__ void stage16_f32(const float* __restrict__ g, u16* s){
  float4 a0 = ((const float4*)g)[0];
  float4 a1 = ((const float4*)g)[1];
  float4 a2 = ((const float4*)g)[2];
  float4 a3 = ((const float4*)g)[3];
  *(uint2*)(s+0)  = make_uint2(pk2(a0.x,a0.y), pk2(a0.z,a0.w));
  *(uint2*)(s+4)  = make_uint2(pk2(a1.x,a1.y), pk2(a1.z,a1.w));
  *(uint2*)(s+8)  = make_uint2(pk2(a2.x,a2.y), pk2(a2.z,a2.w));
  *(uint2*)(s+12) = make_uint2(pk2(a3.x,a3.y), pk2(a3.z,a3.w));
}

union AFU { bf16x8 f; u32 u[4]; };

// prep: z=0..3 -> weight transpose (f32/bf16 -> bf16, [k][n] -> [n][k]);
//       z=4..6 -> activation f32->bf16 convert (skipped when input is bf16).
__global__ __launch_bounds__(256) void prep(
    const void* __restrict__ w0, const void* __restrict__ w1,
    const void* __restrict__ w2, const void* __restrict__ w3,
    u16* t0, u16* t1, u16* t2, u16* t3,
    const void* __restrict__ a0, const void* __restrict__ a1,
    const void* __restrict__ a2,
    u16* c0, u16* c1, u16* c2, const int f32f){
  __shared__ u16 tile[32][33];
  int z = blockIdx.z;
  int tid = threadIdx.x;
  bool f32 = f32f != 0;
  if (z < 4){
    const void* in = z==0?w0 : z==1?w1 : z==2?w2 : w3;
    u16* out = z==0?t0 : z==1?t1 : z==2?t2 : t3;
    int tx = tid & 31, ty = tid >> 5;
    int c  = blockIdx.x*32 + tx;
    int r0 = blockIdx.y*32;
    for (int i=ty;i<32;i+=8){
      long off = (long)(r0+i)*DM + c;
      tile[i][tx] = f32 ? f2bf(((const float*)in)[off]) : ((const u16*)in)[off];
    }
    __syncthreads();
    int rr = r0 + tx, cb = blockIdx.x*32;
    for (int i=ty;i<32;i+=8) out[(long)(cb+i)*DM + rr] = tile[tx][i];
  } else {
    if (!f32) return;
    const void* in = z==4?a0 : z==5?a1 : a2;
    u16* out = z==4?c0 : z==5?c1 : c2;
    long lb = (long)blockIdx.y*32 + blockIdx.x;     // 0..1023
    long base = (lb*256 + tid)*8;
    #pragma unroll
    for (int it=0; it<4; it++){
      long i = base + (long)it*2097152;
      const float4* p = (const float4*)((const float*)in + i);
      float4 x = p[0], y = p[1];
      *(uint4*)(out + i) = make_uint4(pk2(x.x,x.y), pk2(x.z,x.w), pk2(y.x,y.y), pk2(y.z,y.w));
    }
  }
}

// Fused QKV projection: z=0 -> Q (scaled by CS), z=1 -> K, z=2 -> V (written
// transposed per head with in-tile key permutation sigma:
//   n = rt*16 + q*4 + r  ->  p = 32*(rt>>1) + 8*q + 4*(rt&1) + r
// matching the attention kernel's in-register P fragment order.
// 128x128 tile, 4 waves, BK=32. ADMA=1: A is bf16, both operands DMA-staged
// with double-buffered LDS + counted vmcnt (2-phase pipeline).
template<int ADMA>
__global__ __launch_bounds__(256) void gemm_qkv(
    const void* __restrict__ A0, const void* __restrict__ A1, const void* __restrict__ A2,
    const u16* __restrict__ W0, const u16* __restrict__ W1, const u16* __restrict__ W2,
    const void* __restrict__ bv0, const void* __restrict__ bv1, const void* __restrict__ bv2,
    u16* C0, u16* C1, u16* C2, const int f32f){
  constexpr int AST = ADMA ? 32 : 36;
  constexpr int NB  = ADMA ? 2 : 1;
  __shared__ __align__(16) u16 As[NB][128*AST];
  __shared__ __align__(16) u16 Bs[NB][128*32];
  int z = blockIdx.z;
  const void* A  = z==0?A0 : z==1?A1 : A2;
  const u16* BT  = z==0?W0 : z==1?W1 : W2;
  const void* bias = z==0?bv0 : z==1?bv1 : bv2;
  u16* C = z==0?C0 : z==1?C1 : C2;
  const bool aF32 = (!ADMA) && (f32f != 0);
  const bool bF32 = (f32f != 0);
  int tid = threadIdx.x;
  int by = blockIdx.x, bx = blockIdx.y;
  int lane = tid & 63, w = tid >> 6;
  int t = lane & 15, q = lane >> 4;
  int wr = w >> 1, wc = w & 1;
  f32x4 acc[4][4];
  #pragma unroll
  for(int i=0;i<4;i++) for(int j=0;j<4;j++) for(int k=0;k<4;k++) acc[i][j][k]=0.f;

  const u16* gB = BT + ((long)(bx*128 + w*32 + (lane>>2))*DM + (lane&3)*8);

  if constexpr (ADMA){
    const u16* gA = (const u16*)A + ((long)(by*128 + w*32 + (lane>>2))*DM + (lane&3)*8);
    const int lb = (w*32)*32;               // wave-uniform stripe base (u16)
    // prologue: tile 0 -> buf 0
    dma16(gA,         &As[0][lb]);
    dma16(gA + 16*DM, &As[0][lb + 16*32]);
    dma16(gB,         &Bs[0][lb]);
    dma16(gB + 16*DM, &Bs[0][lb + 16*32]);
    for (int k0=0; k0<DM; k0+=32){
      int cur = (k0>>5)&1;
      if (k0+32 < DM){
        dma16(gA + k0+32,         &As[cur^1][lb]);
        dma16(gA + k0+32 + 16*DM, &As[cur^1][lb + 16*32]);
        dma16(gB + k0+32,         &Bs[cur^1][lb]);
        dma16(gB + k0+32 + 16*DM, &Bs[cur^1][lb + 16*32]);
        asm volatile("s_waitcnt vmcnt(4)" ::: "memory");   // tile k0 landed
      } else {
        asm volatile("s_waitcnt vmcnt(0)" ::: "memory");
      }
      __builtin_amdgcn_s_barrier();
      bf16x8 af[4], bfr[4];
      const u16* Ar = &As[cur][(wr*64 + t)*32 + q*8];
      const u16* Br = &Bs[cur][(wc*64 + t)*32 + q*8];
      #pragma unroll
      for (int rt=0;rt<4;rt++) af[rt]  = frag16v(Ar + rt*16*32);
      #pragma unroll
      for (int ct=0;ct<4;ct++) bfr[ct] = frag16v(Br + ct*16*32);
      #pragma unroll
      for (int rt=0;rt<4;rt++)
        #pragma unroll
        for (int ct=0;ct<4;ct++)
          acc[rt][ct] = __builtin_amdgcn_mfma_f32_16x16x32_bf16(af[rt], bfr[ct], acc[rt][ct], 0,0,0);
      __builtin_amdgcn_s_barrier();
    }
  } else {
    long aoff = (long)(by*128 + (tid>>1))*DM + (tid&1)*16;
    const u16* ArdB = &As[0][(wr*64 + t)*AST + q*8];
    const u16* BrdB = &Bs[0][(wc*64 + t)*32  + q*8];
    for (int k0=0; k0<DM; k0+=32){
      dma16(gB + k0,         &Bs[0][(w*32)*32]);
      dma16(gB + 16*DM + k0, &Bs[0][(w*32)*32 + 16*32]);
      u16* AsW = &As[0][(tid>>1)*36 + (tid&1)*16];
      if (aF32) stage16_f32((const float*)A + aoff + k0, AsW);
      else      stage16_bf ((const u16*)A  + aoff + k0, AsW);
      __syncthreads();
      bf16x8 af[4], bfr[4];
      #pragma unroll
      for (int rt=0;rt<4;rt++) af[rt]  = lds_frag(ArdB + rt*16*AST);
      #pragma unroll
      for (int ct=0;ct<4;ct++) bfr[ct] = lds_frag(BrdB + ct*16*32);
      #pragma unroll
      for (int rt=0;rt<4;rt++)
        #pragma unroll
        for (int ct=0;ct<4;ct++)
          acc[rt][ct] = __builtin_amdgcn_mfma_f32_16x16x32_bf16(af[rt], bfr[ct], acc[rt][ct], 0,0,0);
      __syncthreads();
    }
  }

  float scale = (z==0) ? CS : 1.0f;
  #pragma unroll
  for (int ct=0;ct<4;ct++){
    int col = bx*128 + wc*64 + ct*16 + t;
    float bvv = bF32 ? ((const float*)bias)[col] : bf2f(((const u16*)bias)[col]);
    #pragma unroll
    for (int rt=0;rt<4;rt++){
      int row0 = by*128 + wr*64 + rt*16 + q*4;
      if (z == 2){
        int bb = row0 >> 11, s = row0 & 2047;
        long vbase = (long)bb*2097152 + (long)col*2048
                   + (s & ~63) + ((rt>>1)<<5) + (q<<3) + ((rt&1)<<2);
        u32 lo = pk2(acc[rt][ct][0]+bvv, acc[rt][ct][1]+bvv);
        u32 hi = pk2(acc[rt][ct][2]+bvv, acc[rt][ct][3]+bvv);
        *(uint2*)(C + vbase) = make_uint2(lo,hi);
      } else {
        #pragma unroll
        for (int r=0;r<4;r++)
          C[(long)(row0+r)*DM + col] = f2bf((acc[rt][ct][r] + bvv)*scale);
      }
    }
  }
}

// Output projection: A bf16 in ws, both operands DMA-staged, double-buffered.
__global__ __launch_bounds__(256) void gemm_o(const u16* __restrict__ A,
    const u16* __restrict__ BT, const void* __restrict__ bias, void* __restrict__ C,
    const int f32f){
  __shared__ __align__(16) u16 As[2][128*32];
  __shared__ __align__(16) u16 Bs[2][128*32];
  const int f = f32f;
  int tid = threadIdx.x;
  int by = blockIdx.x, bx = blockIdx.y;
  int lane = tid & 63, w = tid >> 6;
  int t = lane & 15, q = lane >> 4;
  int wr = w >> 1, wc = w & 1;
  f32x4 acc[4][4];
  #pragma unroll
  for(int i=0;i<4;i++) for(int j=0;j<4;j++) for(int k=0;k<4;k++) acc[i][j][k]=0.f;

  const u16* gA = A  + ((long)(by*128 + w*32 + (lane>>2))*DM + (lane&3)*8);
  const u16* gB = BT + ((long)(bx*128 + w*32 + (lane>>2))*DM + (lane&3)*8);
  const int lb = (w*32)*32;
  // prologue: tile 0 -> buf 0
  dma16(gA,         &As[0][lb]);
  dma16(gA + 16*DM, &As[0][lb + 16*32]);
  dma16(gB,         &Bs[0][lb]);
  dma16(gB + 16*DM, &Bs[0][lb + 16*32]);
  for (int k0=0; k0<DM; k0+=32){
    int cur = (k0>>5)&1;
    if (k0+32 < DM){
      dma16(gA + k0+32,         &As[cur^1][lb]);
      dma16(gA + k0+32 + 16*DM, &As[cur^1][lb + 16*32]);
      dma16(gB + k0+32,         &Bs[cur^1][lb]);
      dma16(gB + k0+32 + 16*DM, &Bs[cur^1][lb + 16*32]);
      asm volatile("s_waitcnt vmcnt(4)" ::: "memory");
    } else {
      asm volatile("s_waitcnt vmcnt(0)" ::: "memory");
    }
    __builtin_amdgcn_s_barrier();
    bf16x8 af[4], bfr[4];
    const u16* Ar = &As[cur][(wr*64 + t)*32 + q*8];
    const u16* Br = &Bs[cur][(wc*64 + t)*32 + q*8];
    #pragma unroll
    for (int rt=0;rt<4;rt++) af[rt]  = frag16v(Ar + rt*16*32);
    #pragma unroll
    for (int ct=0;ct<4;ct++) bfr[ct] = frag16v(Br + ct*16*32);
    #pragma unroll
    for (int rt=0;rt<4;rt++)
      #pragma unroll
      for (int ct=0;ct<4;ct++)
        acc[rt][ct] = __builtin_amdgcn_mfma_f32_16x16x32_bf16(af[rt], bfr[ct], acc[rt][ct], 0,0,0);
    __builtin_amdgcn_s_barrier();
  }
  #pragma unroll
  for (int ct=0;ct<4;ct++){
    int col = bx*128 + wc*64 + ct*16 + t;
    float bvv = f ? ((const float*)bias)[col] : bf2f(((const u16*)bias)[col]);
    #pragma unroll
    for (int rt=0;rt<4;rt++){
      int row0 = by*128 + wr*64 + rt*16 + q*4;
      #pragma unroll
      for (int r=0;r<4;r++){
        long idx = (long)(row0+r)*DM + col;
        float v = acc[rt][ct][r] + bvv;
        if (f) ((float*)C)[idx] = v;
        else   ((u16*)C)[idx]  = f2bf(v);
      }
    }
  }
}

// ---- attention building blocks (16x16x32, swapped QK, sigma-permuted V) ----
static __device__ __forceinline__ void qk16(const u16* Kc, int t, int q, int xorv,
    const bf16x8 (&qf)[2][2], f32x4 (&sacc)[2][4]){
  #pragma unroll
  for (int i=0;i<2;i++)
    #pragma unroll
    for (int j=0;j<4;j++)
      #pragma unroll
      for (int k=0;k<4;k++) sacc[i][j][k]=0.f;
  #pragma unroll
  for (int ks=0; ks<2; ks++){
    int off = ((ks*64 + q*16) ^ xorv) >> 1;
    bf16x8 k0 = frag16v(Kc + (t     )*64 + off);
    bf16x8 k1 = frag16v(Kc + (16 + t)*64 + off);
    bf16x8 k2 = frag16v(Kc + (32 + t)*64 + off);
    bf16x8 k3 = frag16v(Kc + (48 + t)*64 + off);
    __builtin_amdgcn_s_setprio(1);
    #pragma unroll
    for (int rt=0; rt<2; rt++){
      sacc[rt][0] = __builtin_amdgcn_mfma_f32_16x16x32_bf16(k0, qf[rt][ks], sacc[rt][0],0,0,0);
      sacc[rt][1] = __builtin_amdgcn_mfma_f32_16x16x32_bf16(k1, qf[rt][ks], sacc[rt][1],0,0,0);
      sacc[rt][2] = __builtin_amdgcn_mfma_f32_16x16x32_bf16(k2, qf[rt][ks], sacc[rt][2],0,0,0);
      sacc[rt][3] = __builtin_amdgcn_mfma_f32_16x16x32_bf16(k3, qf[rt][ks], sacc[rt][3],0,0,0);
    }
    __builtin_amdgcn_s_setprio(0);
  }
}

static __device__ __forceinline__ void sm16(const f32x4 (&sacc)[2][4], AFU (&af)[2][2]){
  #pragma unroll
  for (int rt=0; rt<2; rt++){
    float ev[4][4];
    #pragma unroll
    for (int c=0; c<4; c++)
      #pragma unroll
      for (int r=0; r<4; r++) ev[c][r] = EXP2F(sacc[rt][c][r]);
    #pragma unroll
    for (int ks=0; ks<2; ks++){
      af[rt][ks].u[0] = pk2(ev[2*ks  ][0], ev[2*ks  ][1]);
      af[rt][ks].u[1] = pk2(ev[2*ks  ][2], ev[2*ks  ][3]);
      af[rt][ks].u[2] = pk2(ev[2*ks+1][0], ev[2*ks+1][1]);
      af[rt][ks].u[3] = pk2(ev[2*ks+1][2], ev[2*ks+1][3]);
    }
  }
}

static __device__ __forceinline__ void pv16(const u16* Vc, int t, int q, int xorv,
    const AFU (&af)[2][2], bf16x8 vonef, f32x4 (&o)[2][4], f32x4 (&o4)[2]){
  #pragma unroll
  for (int ks=0; ks<2; ks++){
    int off = ((ks*64 + q*16) ^ xorv) >> 1;
    bf16x8 v0 = frag16v(Vc + (t     )*64 + off);
    bf16x8 v1 = frag16v(Vc + (16 + t)*64 + off);
    bf16x8 v2 = frag16v(Vc + (32 + t)*64 + off);
    bf16x8 v3 = frag16v(Vc + (48 + t)*64 + off);
    __builtin_amdgcn_s_setprio(1);
    #pragma unroll
    for (int rt=0; rt<2; rt++){
      o[rt][0] = __builtin_amdgcn_mfma_f32_16x16x32_bf16(af[rt][ks].f, v0, o[rt][0],0,0,0);
      o[rt][1] = __builtin_amdgcn_mfma_f32_16x16x32_bf16(af[rt][ks].f, v1, o[rt][1],0,0,0);
      o[rt][2] = __builtin_amdgcn_mfma_f32_16x16x32_bf16(af[rt][ks].f, v2, o[rt][2],0,0,0);
      o[rt][3] = __builtin_amdgcn_mfma_f32_16x16x32_bf16(af[rt][ks].f, v3, o[rt][3],0,0,0);
      o4[rt]   = __builtin_amdgcn_mfma_f32_16x16x32_bf16(af[rt][ks].f, vonef, o4[rt],0,0,0);
    }
    __builtin_amdgcn_s_setprio(0);
  }
}

// Flash attention v7: pipelined QK(kt) || PV(kt-1) || SM(kt), ONE barrier/iter.
// K double-buffered, V TRIPLE-buffered (PV lags one tile, so the V write slot
// (kt+1)%3 never collides with the PV read slot (kt-1)%3). All prefetches are
// issued AFTER the barrier -> race-free (all waves finished reading the target
// slot before the barrier). vmcnt(2) before the barrier gives each wave's
// loads cross-wave visibility; every load has a full compute phase to land.
// LDS = 40KB -> 4 blocks/CU.
__global__ __launch_bounds__(256,4) void attn7(const u16* __restrict__ Q,
    const u16* __restrict__ Kb, const u16* __restrict__ Vt, u16* __restrict__ O){
  __shared__ __align__(16) u16 SM_[20480];   // K: [0|4096], V: [8192|12288|16384]
  int tid = threadIdx.x;
  int bid = blockIdx.x;
  int qt = bid >> 6;
  int s6 = bid & 63;
  int bh = (s6 & 7)*8 + (s6 >> 3);   // all 16 qt-blocks of a bh -> same XCD
  int b = bh >> 4, h = bh & 15;
  int lane = tid & 63, w = tid >> 6;
  int t = lane & 15, q = lane >> 4;

  const u16* Qbase = Q + ((long)(b*S_ + qt*128 + w*32 + t)*DM + h*DH + q*8);
  bf16x8 qf[2][2];
  qf[0][0] = frag16v(Qbase);
  qf[0][1] = frag16v(Qbase + 32);
  qf[1][0] = frag16v(Qbase + 16*DM);
  qf[1][1] = frag16v(Qbase + 16*DM + 32);

  int r0 = tid >> 3;
  int cb = ((tid & 7) * 16) ^ ((r0 & 7) << 4);
  const char* gK = (const char*)Kb + (((long)(b*S_ + r0)*DM + h*DH) << 1) + cb;
  const char* gV = (const char*)Vt + ((((long)bh << 17) + ((long)r0 << 11)) << 1) + cb;
  const long gK1 = ((long)32*DM) << 1;     // +32 s-rows
  const long gV1 = ((long)32*S_) << 1;     // +32 dh-rows
  const long KT  = ((long)64*DM) << 1;     // one K tile
  const int ld0 = w*512, ld1 = 2048 + w*512;

  f32x4 o[2][4];
  #pragma unroll
  for (int i=0;i<2;i++)
    #pragma unroll
    for (int j=0;j<4;j++)
      #pragma unroll
      for (int k=0;k<4;k++) o[i][j][k]=0.f;
  f32x4 o4[2];
  #pragma unroll
  for (int i=0;i<2;i++)
    #pragma unroll
    for (int k=0;k<4;k++) o4[i][k]=0.f;

  union { bf16x8 f; u32 u[4]; } vone;
  { u32 ovv = (t==0) ? 0x3F803F80u : 0u;
    vone.u[0]=ovv; vone.u[1]=ovv; vone.u[2]=ovv; vone.u[3]=ovv; }

  const int xorv = (t & 7) << 4;

  // prologue: K0->k0, V0->v0, K1->k1, V1->v1 (queue: 8)
  dma16((const u16*)(gK),              &SM_[ld0]);
  dma16((const u16*)(gK + gK1),        &SM_[ld1]);
  dma16((const u16*)(gV),              &SM_[ 8192 + ld0]);
  dma16((const u16*)(gV + gV1),        &SM_[ 8192 + ld1]);
  dma16((const u16*)(gK + KT),         &SM_[ 4096 + ld0]);
  dma16((const u16*)(gK + KT + gK1),   &SM_[ 4096 + ld1]);
  dma16((const u16*)(gV + (1L<<7)),        &SM_[12288 + ld0]);
  dma16((const u16*)(gV + (1L<<7) + gV1),  &SM_[12288 + ld1]);
  asm volatile("s_waitcnt vmcnt(6)" ::: "memory");   // K0 landed
  __builtin_amdgcn_s_barrier();

  f32x4 sacc[2][4];
  AFU af[2][2];
  qk16(&SM_[0], t, q, xorv, qf, sacc);
  sm16(sacc, af);

  int ka = 4096, kb = 0;                  // K read / write slots
  int va = 8192, vb = 12288, vc = 16384;  // V: read(kt-1) / kt / write(kt+1)
  for (int kt = 1; kt < 32; kt++){
    // drain to 2: K(kt) and V(kt-1) (and older) landed for every wave
    asm volatile("s_waitcnt vmcnt(2)" ::: "memory");
    __builtin_amdgcn_s_barrier();
    if (kt <= 30){                        // prefetch K(kt+1), V(kt+1)
      const char* g = gK + (long)(kt+1)*KT;
      dma16((const u16*)(g),       &SM_[kb + ld0]);
      dma16((const u16*)(g + gK1), &SM_[kb + ld1]);
      const char* gv2 = gV + ((long)(kt+1) << 7);
      dma16((const u16*)(gv2),       &SM_[vc + ld0]);
      dma16((const u16*)(gv2 + gV1), &SM_[vc + ld1]);
    }
    qk16(&SM_[ka], t, q, xorv, qf, sacc);
    pv16(&SM_[va], t, q, xorv, af, vone.f, o, o4);
    sm16(sacc, af);
    int tk = ka; ka = kb; kb = tk;
    int tv = va; va = vb; vb = vc; vc = tv;
  }
  // after final rotation va = slot(31%3): PV(31)
  asm volatile("s_waitcnt vmcnt(0)" ::: "memory");
  __builtin_amdgcn_s_barrier();
  pv16(&SM_[va], t, q, xorv, af, vone.f, o, o4);

  #pragma unroll
  for (int rt=0; rt<2; rt++){
    #pragma unroll
    for (int r=0; r<4; r++){
      float l = __shfl(o4[rt][r], lane & 48);
      float inv = 1.f / l;
      int row = qt*128 + w*32 + rt*16 + q*4 + r;
      #pragma unroll
      for (int ct=0; ct<4; ct++)
        O[(long)(b*S_ + row)*DM + h*DH + ct*16 + t] = f2bf(o[rt][ct][r] * inv);
    }
  }
}

extern "C" void kernel_launch(void* const* d_in, const int* in_sizes, int n_in,
                              void* d_out, int out_size, void* d_ws, size_t ws_size,
                              hipStream_t stream){
  (void)n_in; (void)out_size;
  const void* xq = d_in[0];
  const void* xk = d_in[1];
  const void* xv = d_in[2];
  const void* Wq = d_in[3];
  const void* bq = d_in[4];
  const void* Wk = d_in[5];
  const void* bk = d_in[6];
  const void* Wv = d_in[7];
  const void* bv = d_in[8];
  const void* Wo = d_in[9];
  const void* bo = d_in[10];

  // dtype from host-side size: bf16 iff input 0 is exactly NT*2 bytes.
  const long NT = (long)BS*DM;                    // 8,388,608 elements
  int f32f = 1;
  if (in_sizes && in_sizes[0] == (int)(NT*2)) f32f = 0;

  u16* base = (u16*)((char*)d_ws + 256);
  u16* Qb  = base;                                // Q (scaled), later attention O
  u16* Kbf = base + NT;
  u16* Vt  = base + 2*NT;                         // [b*16+h][64][2048], sigma-permuted
  u16* WqT = base + 3*NT;
  u16* WkT = WqT + (long)DM*DM;
  u16* WvT = WkT + (long)DM*DM;
  u16* WoT = WvT + (long)DM*DM;
  u16* Xc0 = WoT + (long)DM*DM;                   // bf16-converted activations
  u16* Xc1 = Xc0 + NT;
  u16* Xc2 = Xc1 + NT;
  size_t need_pre = 256 + (size_t)(6*NT + 4*(long)DM*DM)*2;   // ~109 MB
  bool pre = ws_size >= need_pre;

  dim3 gb(256,1,1);
  int nz = (pre && f32f) ? 7 : 4;
  prep<<<dim3(32,32,nz), gb, 0, stream>>>(Wq, Wk, Wv, Wo,
      WqT, WkT, WvT, WoT, xq, xk, xv, Xc0, Xc1, Xc2, f32f);

  if (pre){
    const void* Aq = f32f ? (const void*)Xc0 : xq;
    const void* Ak = f32f ? (const void*)Xc1 : xk;
    const void* Av = f32f ? (const void*)Xc2 : xv;
    gemm_qkv<1><<<dim3(64,8,3), gb, 0, stream>>>(Aq, Ak, Av,
        WqT, WkT, WvT, bq, bk, bv, Qb, Kbf, Vt, f32f);
  } else {
    gemm_qkv<0><<<dim3(64,8,3), gb, 0, stream>>>(xq, xk, xv,
        WqT, WkT, WvT, bq, bk, bv, Qb, Kbf, Vt, f32f);
  }

  attn7<<<dim3(1024,1,1), gb, 0, stream>>>(Qb, Kbf, Vt, Qb /* O reuses Q */);

  gemm_o<<<dim3(64,8,1), gb, 0, stream>>>(Qb, WoT, bo, d_out, f32f);
}

// Round 6
// 383.407 us; speedup vs baseline: 1.0099x; 1.0099x over previous
//
#include <hip/hip_runtime.h>

typedef unsigned short u16;
typedef unsigned int   u32;
typedef unsigned long long u64;
typedef __attribute__((ext_vector_type(8))) short bf16x8;
typedef __attribute__((ext_vector_type(4))) float f32x4;

#define S_  2048
#define DH  64
#define DM  1024
#define BS  8192
#define CS  0.18033688011112042f   // 0.125 * log2(e)

static __device__ __forceinline__ float bf2f(u16 v){ return __uint_as_float(((u32)v)<<16); }
static __device__ __forceinline__ u16 f2bf(float f){
  u32 x = __float_as_uint(f);
  return (u16)((x + 0x7fffu + ((x>>16)&1u)) >> 16);   // RNE
}
#if __has_builtin(__builtin_amdgcn_cvt_pk_bf16_f32)
static __device__ __forceinline__ u32 pk2(float x, float y){
  typedef __attribute__((ext_vector_type(2))) __bf16 bf2v;
  union { bf2v v; u32 u; } c; c.v = __builtin_amdgcn_cvt_pk_bf16_f32(x, y); return c.u;
}
#else
static __device__ __forceinline__ u32 pk2(float x, float y){
  return (u32)f2bf(x) | ((u32)f2bf(y) << 16);
}
#endif
#if __has_builtin(__builtin_amdgcn_exp2f)
#define EXP2F(x) __builtin_amdgcn_exp2f(x)
#else
#define EXP2F(x) exp2f(x)
#endif

// async global->LDS, 16B/lane; LDS dest = wave-uniform base + lane*16
static __device__ __forceinline__ void dma16(const u16* g, const u16* l){
  __builtin_amdgcn_global_load_lds(
      (const __attribute__((address_space(1))) u32*)(u64)(uintptr_t)g,
      (__attribute__((address_space(3))) u32*)(u32)(u64)(uintptr_t)l, 16, 0, 0);
}

static __device__ __forceinline__ bf16x8 lds_frag(const u16* p){
  union { bf16x8 f; uint2 u[2]; } w;
  w.u[0] = *(const uint2*)(p);
  w.u[1] = *(const uint2*)(p+4);
  return w.f;
}
// 16B-aligned fragment load (single ds_read_b128)
static __device__ __forceinline__ bf16x8 frag16v(const u16* p){
  union { bf16x8 f; uint4 u; } w;
  w.u = *(const uint4*)p;
  return w.f;
}
static __device__ __forceinline__ void stage16_bf(const u16* __restrict__ g, u16* s){
  uint4 a = *(const uint4*)g;
  uint4 b = *(const uint4*)(g+8);
  *(uint2*)(s+0)  = make_uint2(a.x,a.y);
  *(uint2*)(s+4)  = make_uint2(a.z,a.w);
  *(uint2*)(s+8)  = make_uint2(b.x,b.y);
  *(uint2*)(s+12) = make_uint2(b.z,b.w);
}
static __device__ __forceinline__ void stage16_f32(const float* __restrict__ g, u16* s){
  float4 a0 = ((const float4*)g)[0];
  float4 a1 = ((const float4*)g)[1];
  float4 a2 = ((const float4*)g)[2];
  float4 a3 = ((const float4*)g)[3];
  *(uint2*)(s+0)  = make_uint2(pk2(a0.x,a0.y), pk2(a0.z,a0.w));
  *(uint2*)(s+4)  = make_uint2(pk2(a1.x,a1.y), pk2(a1.z,a1.w));
  *(uint2*)(s+8)  = make_uint2(pk2(a2.x,a2.y), pk2(a2.z,a2.w));
  *(uint2*)(s+12) = make_uint2(pk2(a3.x,a3.y), pk2(a3.z,a3.w));
}

// prep: z=0..3 -> weight transpose (f32/bf16 -> bf16, [k][n] -> [n][k]);
//       z=4..6 -> activation f32->bf16 convert (skipped when input is bf16).
__global__ __launch_bounds__(256) void prep(
    const void* __restrict__ w0, const void* __restrict__ w1,
    const void* __restrict__ w2, const void* __restrict__ w3,
    u16* t0, u16* t1, u16* t2, u16* t3,
    const void* __restrict__ a0, const void* __restrict__ a1,
    const void* __restrict__ a2,
    u16* c0, u16* c1, u16* c2, const int f32f){
  __shared__ u16 tile[32][33];
  int z = blockIdx.z;
  int tid = threadIdx.x;
  bool f32 = f32f != 0;
  if (z < 4){
    const void* in = z==0?w0 : z==1?w1 : z==2?w2 : w3;
    u16* out = z==0?t0 : z==1?t1 : z==2?t2 : t3;
    int tx = tid & 31, ty = tid >> 5;
    int c  = blockIdx.x*32 + tx;
    int r0 = blockIdx.y*32;
    for (int i=ty;i<32;i+=8){
      long off = (long)(r0+i)*DM + c;
      tile[i][tx] = f32 ? f2bf(((const float*)in)[off]) : ((const u16*)in)[off];
    }
    __syncthreads();
    int rr = r0 + tx, cb = blockIdx.x*32;
    for (int i=ty;i<32;i+=8) out[(long)(cb+i)*DM + rr] = tile[tx][i];
  } else {
    if (!f32) return;
    const void* in = z==4?a0 : z==5?a1 : a2;
    u16* out = z==4?c0 : z==5?c1 : c2;
    long lb = (long)blockIdx.y*32 + blockIdx.x;     // 0..1023
    long base = (lb*256 + tid)*8;
    #pragma unroll
    for (int it=0; it<4; it++){
      long i = base + (long)it*2097152;
      const float4* p = (const float4*)((const float*)in + i);
      float4 x = p[0], y = p[1];
      *(uint4*)(out + i) = make_uint4(pk2(x.x,x.y), pk2(x.z,x.w), pk2(y.x,y.y), pk2(y.z,y.w));
    }
  }
}

// Fused QKV projection: z=0 -> Q (scaled by CS), z=1 -> K, z=2 -> V (written
// transposed per head with in-tile key permutation sigma:
//   n = rt*16 + q*4 + r  ->  p = 32*(rt>>1) + 8*q + 4*(rt&1) + r
// matching the attention kernel's in-register P fragment order.
// 128x128 tile, 4 waves, BK=32. ADMA=1: A is bf16, both operands DMA-staged
// with double-buffered LDS + counted vmcnt (2-phase pipeline).
// Each block computes TWO adjacent by-tiles (grid.x = 32): 768 blocks total
// -> 3 blocks/CU all-resident, no dispatch tail; B panel reused across subs.
template<int ADMA>
__global__ __launch_bounds__(256) void gemm_qkv(
    const void* __restrict__ A0, const void* __restrict__ A1, const void* __restrict__ A2,
    const u16* __restrict__ W0, const u16* __restrict__ W1, const u16* __restrict__ W2,
    const void* __restrict__ bv0, const void* __restrict__ bv1, const void* __restrict__ bv2,
    u16* C0, u16* C1, u16* C2, const int f32f){
  constexpr int AST = ADMA ? 32 : 36;
  constexpr int NB  = ADMA ? 2 : 1;
  __shared__ __align__(16) u16 As[NB][128*AST];
  __shared__ __align__(16) u16 Bs[NB][128*32];
  int z = blockIdx.z;
  const void* A  = z==0?A0 : z==1?A1 : A2;
  const u16* BT  = z==0?W0 : z==1?W1 : W2;
  const void* bias = z==0?bv0 : z==1?bv1 : bv2;
  u16* C = z==0?C0 : z==1?C1 : C2;
  const bool aF32 = (!ADMA) && (f32f != 0);
  const bool bF32 = (f32f != 0);
  int tid = threadIdx.x;
  int bx = blockIdx.y;
  int lane = tid & 63, w = tid >> 6;
  int t = lane & 15, q = lane >> 4;
  int wr = w >> 1, wc = w & 1;

  const u16* gB = BT + ((long)(bx*128 + w*32 + (lane>>2))*DM + (lane&3)*8);
  float scale = (z==0) ? CS : 1.0f;

  for (int sub = 0; sub < 2; ++sub){
    int by = blockIdx.x*2 + sub;
    f32x4 acc[4][4];
    #pragma unroll
    for(int i=0;i<4;i++) for(int j=0;j<4;j++) for(int k=0;k<4;k++) acc[i][j][k]=0.f;

    if constexpr (ADMA){
      const u16* gA = (const u16*)A + ((long)(by*128 + w*32 + (lane>>2))*DM + (lane&3)*8);
      const int lb = (w*32)*32;               // wave-uniform stripe base (u16)
      // prologue: tile 0 -> buf 0
      dma16(gA,         &As[0][lb]);
      dma16(gA + 16*DM, &As[0][lb + 16*32]);
      dma16(gB,         &Bs[0][lb]);
      dma16(gB + 16*DM, &Bs[0][lb + 16*32]);
      for (int k0=0; k0<DM; k0+=32){
        int cur = (k0>>5)&1;
        if (k0+32 < DM){
          dma16(gA + k0+32,         &As[cur^1][lb]);
          dma16(gA + k0+32 + 16*DM, &As[cur^1][lb + 16*32]);
          dma16(gB + k0+32,         &Bs[cur^1][lb]);
          dma16(gB + k0+32 + 16*DM, &Bs[cur^1][lb + 16*32]);
          asm volatile("s_waitcnt vmcnt(4)" ::: "memory");   // tile k0 landed
        } else {
          asm volatile("s_waitcnt vmcnt(0)" ::: "memory");
        }
        __builtin_amdgcn_s_barrier();
        bf16x8 af[4], bfr[4];
        const u16* Ar = &As[cur][(wr*64 + t)*32 + q*8];
        const u16* Br = &Bs[cur][(wc*64 + t)*32 + q*8];
        #pragma unroll
        for (int rt=0;rt<4;rt++) af[rt]  = frag16v(Ar + rt*16*32);
        #pragma unroll
        for (int ct=0;ct<4;ct++) bfr[ct] = frag16v(Br + ct*16*32);
        #pragma unroll
        for (int rt=0;rt<4;rt++)
          #pragma unroll
          for (int ct=0;ct<4;ct++)
            acc[rt][ct] = __builtin_amdgcn_mfma_f32_16x16x32_bf16(af[rt], bfr[ct], acc[rt][ct], 0,0,0);
        __builtin_amdgcn_s_barrier();
      }
    } else {
      long aoff = (long)(by*128 + (tid>>1))*DM + (tid&1)*16;
      const u16* ArdB = &As[0][(wr*64 + t)*AST + q*8];
      const u16* BrdB = &Bs[0][(wc*64 + t)*32  + q*8];
      for (int k0=0; k0<DM; k0+=32){
        dma16(gB + k0,         &Bs[0][(w*32)*32]);
        dma16(gB + 16*DM + k0, &Bs[0][(w*32)*32 + 16*32]);
        u16* AsW = &As[0][(tid>>1)*36 + (tid&1)*16];
        if (aF32) stage16_f32((const float*)A + aoff + k0, AsW);
        else      stage16_bf ((const u16*)A  + aoff + k0, AsW);
        __syncthreads();
        bf16x8 af[4], bfr[4];
        #pragma unroll
        for (int rt=0;rt<4;rt++) af[rt]  = lds_frag(ArdB + rt*16*AST);
        #pragma unroll
        for (int ct=0;ct<4;ct++) bfr[ct] = lds_frag(BrdB + ct*16*32);
        #pragma unroll
        for (int rt=0;rt<4;rt++)
          #pragma unroll
          for (int ct=0;ct<4;ct++)
            acc[rt][ct] = __builtin_amdgcn_mfma_f32_16x16x32_bf16(af[rt], bfr[ct], acc[rt][ct], 0,0,0);
        __syncthreads();
      }
    }

    #pragma unroll
    for (int ct=0;ct<4;ct++){
      int col = bx*128 + wc*64 + ct*16 + t;
      float bvv = bF32 ? ((const float*)bias)[col] : bf2f(((const u16*)bias)[col]);
      #pragma unroll
      for (int rt=0;rt<4;rt++){
        int row0 = by*128 + wr*64 + rt*16 + q*4;
        if (z == 2){
          int bb = row0 >> 11, s = row0 & 2047;
          long vbase = (long)bb*2097152 + (long)col*2048
                     + (s & ~63) + ((rt>>1)<<5) + (q<<3) + ((rt&1)<<2);
          u32 lo = pk2(acc[rt][ct][0]+bvv, acc[rt][ct][1]+bvv);
          u32 hi = pk2(acc[rt][ct][2]+bvv, acc[rt][ct][3]+bvv);
          *(uint2*)(C + vbase) = make_uint2(lo,hi);
        } else {
          #pragma unroll
          for (int r=0;r<4;r++)
            C[(long)(row0+r)*DM + col] = f2bf((acc[rt][ct][r] + bvv)*scale);
        }
      }
    }
  }
}

// Output projection: A bf16 in ws, both operands DMA-staged, double-buffered.
__global__ __launch_bounds__(256) void gemm_o(const u16* __restrict__ A,
    const u16* __restrict__ BT, const void* __restrict__ bias, void* __restrict__ C,
    const int f32f){
  __shared__ __align__(16) u16 As[2][128*32];
  __shared__ __align__(16) u16 Bs[2][128*32];
  const int f = f32f;
  int tid = threadIdx.x;
  int by = blockIdx.x, bx = blockIdx.y;
  int lane = tid & 63, w = tid >> 6;
  int t = lane & 15, q = lane >> 4;
  int wr = w >> 1, wc = w & 1;
  f32x4 acc[4][4];
  #pragma unroll
  for(int i=0;i<4;i++) for(int j=0;j<4;j++) for(int k=0;k<4;k++) acc[i][j][k]=0.f;

  const u16* gA = A  + ((long)(by*128 + w*32 + (lane>>2))*DM + (lane&3)*8);
  const u16* gB = BT + ((long)(bx*128 + w*32 + (lane>>2))*DM + (lane&3)*8);
  const int lb = (w*32)*32;
  // prologue: tile 0 -> buf 0
  dma16(gA,         &As[0][lb]);
  dma16(gA + 16*DM, &As[0][lb + 16*32]);
  dma16(gB,         &Bs[0][lb]);
  dma16(gB + 16*DM, &Bs[0][lb + 16*32]);
  for (int k0=0; k0<DM; k0+=32){
    int cur = (k0>>5)&1;
    if (k0+32 < DM){
      dma16(gA + k0+32,         &As[cur^1][lb]);
      dma16(gA + k0+32 + 16*DM, &As[cur^1][lb + 16*32]);
      dma16(gB + k0+32,         &Bs[cur^1][lb]);
      dma16(gB + k0+32 + 16*DM, &Bs[cur^1][lb + 16*32]);
      asm volatile("s_waitcnt vmcnt(4)" ::: "memory");
    } else {
      asm volatile("s_waitcnt vmcnt(0)" ::: "memory");
    }
    __builtin_amdgcn_s_barrier();
    bf16x8 af[4], bfr[4];
    const u16* Ar = &As[cur][(wr*64 + t)*32 + q*8];
    const u16* Br = &Bs[cur][(wc*64 + t)*32 + q*8];
    #pragma unroll
    for (int rt=0;rt<4;rt++) af[rt]  = frag16v(Ar + rt*16*32);
    #pragma unroll
    for (int ct=0;ct<4;ct++) bfr[ct] = frag16v(Br + ct*16*32);
    #pragma unroll
    for (int rt=0;rt<4;rt++)
      #pragma unroll
      for (int ct=0;ct<4;ct++)
        acc[rt][ct] = __builtin_amdgcn_mfma_f32_16x16x32_bf16(af[rt], bfr[ct], acc[rt][ct], 0,0,0);
    __builtin_amdgcn_s_barrier();
  }
  #pragma unroll
  for (int ct=0;ct<4;ct++){
    int col = bx*128 + wc*64 + ct*16 + t;
    float bvv = f ? ((const float*)bias)[col] : bf2f(((const u16*)bias)[col]);
    #pragma unroll
    for (int rt=0;rt<4;rt++){
      int row0 = by*128 + wr*64 + rt*16 + q*4;
      #pragma unroll
      for (int r=0;r<4;r++){
        long idx = (long)(row0+r)*DM + col;
        float v = acc[rt][ct][r] + bvv;
        if (f) ((float*)C)[idx] = v;
        else   ((u16*)C)[idx]  = f2bf(v);
      }
    }
  }
}

// Flash attention v5 (reverted to the proven R2 schedule; no online max; Q
// pre-scaled by CS in projection). Swapped QK^T: mfma(K, Q) puts
// P[qrow=t][key=16c+4q+r] lane-local; V is stored (by gemm_qkv) with the
// sigma key-permutation so PV A-fragments are built entirely in-register
// (cvt_pk only): NO P LDS round-trip. Row sums via a constant ones-column
// B-fragment MFMA (o4). K/V double-buffered in stride-64 LDS via
// global_load_lds with XOR-pre-swizzled source. Two barriers/iter; prefetch
// issued before vmcnt(4) (race-free: the end-of-iteration barrier orders all
// reads of the target buffer before any wave's next-iteration prefetch).
// LDS=32KB -> 4 blocks/CU (grid 1024 = exactly 4/CU, no tail).
__global__ __launch_bounds__(256,4) void attn5(const u16* __restrict__ Q,
    const u16* __restrict__ Kb, const u16* __restrict__ Vt, u16* __restrict__ O){
  __shared__ __align__(16) u16 Ks[2][4096];   // [buf][64 s-rows][64 d], swizzled
  __shared__ __align__(16) u16 Vs[2][4096];   // [buf][64 dh-rows][64 kpos], swizzled
  int tid = threadIdx.x;
  int bid = blockIdx.x;
  int qt = bid >> 6;
  int s6 = bid & 63;
  int bh = (s6 & 7)*8 + (s6 >> 3);   // all 16 qt-blocks of a bh share bid%8 -> same XCD
  int b = bh >> 4, h = bh & 15;
  int lane = tid & 63, w = tid >> 6;
  int t = lane & 15, q = lane >> 4;

  // Q fragments (B-operand): col = qrow = t (+rt*16), k = d = ks*32 + q*8 ..
  const u16* Qbase = Q + ((long)(b*S_ + qt*128 + w*32 + t)*DM + h*DH + q*8);
  bf16x8 qf[2][2];
  qf[0][0] = frag16v(Qbase);
  qf[0][1] = frag16v(Qbase + 32);
  qf[1][0] = frag16v(Qbase + 16*DM);
  qf[1][1] = frag16v(Qbase + 16*DM + 32);

  // DMA chunk mapping: chunk c = tid; row = c>>3, 16B-slot = c&7,
  // global source slot pre-swizzled by row&7 so linear LDS + XOR read works.
  int r0 = tid >> 3;
  int cb = ((tid & 7) * 16) ^ ((r0 & 7) << 4);
  const char* gK = (const char*)Kb + (((long)(b*S_ + r0)*DM + h*DH) << 1) + cb;
  const char* gV = (const char*)Vt + ((((long)bh << 17) + ((long)r0 << 11)) << 1) + cb;
  const long gK1 = ((long)32*DM) << 1;     // +32 s-rows
  const long gV1 = ((long)32*S_) << 1;     // +32 dh-rows
  const int ld0 = w*512, ld1 = 2048 + w*512;   // wave-uniform LDS bases (u16)

  f32x4 o[2][4];
  #pragma unroll
  for (int i=0;i<2;i++) for (int j=0;j<4;j++) for (int k=0;k<4;k++) o[i][j][k]=0.f;
  f32x4 o4[2];
  #pragma unroll
  for (int i=0;i<2;i++) for (int k=0;k<4;k++) o4[i][k]=0.f;

  // ones B-fragment: column 0 all-ones -> o4 row-sums
  union { bf16x8 f; u32 u[4]; } vone;
  { u32 ovv = (t==0) ? 0x3F803F80u : 0u;
    vone.u[0]=ovv; vone.u[1]=ovv; vone.u[2]=ovv; vone.u[3]=ovv; }

  const int xorv = (t & 7) << 4;   // read-side byte XOR (row&7 == t&7 for all frags)

  // prologue: stage tile 0 into buf 0
  dma16((const u16*)(gK),       &Ks[0][ld0]);
  dma16((const u16*)(gK + gK1), &Ks[0][ld1]);
  dma16((const u16*)(gV),       &Vs[0][ld0]);
  dma16((const u16*)(gV + gV1), &Vs[0][ld1]);

  for (int kt=0; kt<32; kt++){
    int cur = kt & 1;
    if (kt < 31){
      long ko = ((long)(kt+1)*64*DM) << 1;   // K advances 64 s-rows
      long vo = (long)(kt+1) << 7;           // V advances 64 key-positions (128 B)
      dma16((const u16*)(gK + ko),       &Ks[cur^1][ld0]);
      dma16((const u16*)(gK + ko + gK1), &Ks[cur^1][ld1]);
      dma16((const u16*)(gV + vo),       &Vs[cur^1][ld0]);
      dma16((const u16*)(gV + vo + gV1), &Vs[cur^1][ld1]);
      asm volatile("s_waitcnt vmcnt(4)" ::: "memory");   // tile kt ready, kt+1 in flight
    } else {
      asm volatile("s_waitcnt vmcnt(0)" ::: "memory");
    }
    __builtin_amdgcn_s_barrier();

    const u16* Kc = Ks[cur];
    const u16* Vc = Vs[cur];

    // QK^T swapped: mfma(K, Q) -> lane (t,q) holds P[qrow=t][key=16c+4q+r]
    f32x4 sacc[2][4];
    #pragma unroll
    for (int i=0;i<2;i++) for (int j=0;j<4;j++) for (int k=0;k<4;k++) sacc[i][j][k]=0.f;
    #pragma unroll
    for (int ks=0; ks<2; ks++){
      int off = ((ks*64 + q*16) ^ xorv) >> 1;
      bf16x8 k0 = frag16v(Kc + (t     )*64 + off);
      bf16x8 k1 = frag16v(Kc + (16 + t)*64 + off);
      bf16x8 k2 = frag16v(Kc + (32 + t)*64 + off);
      bf16x8 k3 = frag16v(Kc + (48 + t)*64 + off);
      __builtin_amdgcn_s_setprio(1);
      #pragma unroll
      for (int rt=0; rt<2; rt++){
        sacc[rt][0] = __builtin_amdgcn_mfma_f32_16x16x32_bf16(k0, qf[rt][ks], sacc[rt][0],0,0,0);
        sacc[rt][1] = __builtin_amdgcn_mfma_f32_16x16x32_bf16(k1, qf[rt][ks], sacc[rt][1],0,0,0);
        sacc[rt][2] = __builtin_amdgcn_mfma_f32_16x16x32_bf16(k2, qf[rt][ks], sacc[rt][2],0,0,0);
        sacc[rt][3] = __builtin_amdgcn_mfma_f32_16x16x32_bf16(k3, qf[rt][ks], sacc[rt][3],0,0,0);
      }
      __builtin_amdgcn_s_setprio(0);
    }

    // softmax (no max-sub) + in-register P->A-fragment pack:
    // af[rt][ks] element e = exp2(sacc[rt][2ks + (e>>2)][e&3])
    union { bf16x8 f; u32 u[4]; } af[2][2];
    #pragma unroll
    for (int rt=0; rt<2; rt++){
      float ev[4][4];
      #pragma unroll
      for (int c=0; c<4; c++)
        #pragma unroll
        for (int r=0; r<4; r++) ev[c][r] = EXP2F(sacc[rt][c][r]);
      #pragma unroll
      for (int ks=0; ks<2; ks++){
        af[rt][ks].u[0] = pk2(ev[2*ks  ][0], ev[2*ks  ][1]);
        af[rt][ks].u[1] = pk2(ev[2*ks  ][2], ev[2*ks  ][3]);
        af[rt][ks].u[2] = pk2(ev[2*ks+1][0], ev[2*ks+1][1]);
        af[rt][ks].u[3] = pk2(ev[2*ks+1][2], ev[2*ks+1][3]);
      }
    }

    // PV: O += P * V ; V columns are sigma-permuted to match af's key order.
    #pragma unroll
    for (int ks=0; ks<2; ks++){
      int off = ((ks*64 + q*16) ^ xorv) >> 1;
      bf16x8 v0 = frag16v(Vc + (t     )*64 + off);
      bf16x8 v1 = frag16v(Vc + (16 + t)*64 + off);
      bf16x8 v2 = frag16v(Vc + (32 + t)*64 + off);
      bf16x8 v3 = frag16v(Vc + (48 + t)*64 + off);
      __builtin_amdgcn_s_setprio(1);
      #pragma unroll
      for (int rt=0; rt<2; rt++){
        o[rt][0] = __builtin_amdgcn_mfma_f32_16x16x32_bf16(af[rt][ks].f, v0, o[rt][0],0,0,0);
        o[rt][1] = __builtin_amdgcn_mfma_f32_16x16x32_bf16(af[rt][ks].f, v1, o[rt][1],0,0,0);
        o[rt][2] = __builtin_amdgcn_mfma_f32_16x16x32_bf16(af[rt][ks].f, v2, o[rt][2],0,0,0);
        o[rt][3] = __builtin_amdgcn_mfma_f32_16x16x32_bf16(af[rt][ks].f, v3, o[rt][3],0,0,0);
        o4[rt]   = __builtin_amdgcn_mfma_f32_16x16x32_bf16(af[rt][ks].f, vone.f, o4[rt],0,0,0);
      }
      __builtin_amdgcn_s_setprio(0);
    }
    __builtin_amdgcn_s_barrier();
  }

  // epilogue: l = row sum (held at lanes t==0 of same q), broadcast, normalize
  #pragma unroll
  for (int rt=0; rt<2; rt++){
    #pragma unroll
    for (int r=0; r<4; r++){
      float l = __shfl(o4[rt][r], lane & 48);
      float inv = 1.f / l;
      int row = qt*128 + w*32 + rt*16 + q*4 + r;
      #pragma unroll
      for (int ct=0; ct<4; ct++)
        O[(long)(b*S_ + row)*DM + h*DH + ct*16 + t] = f2bf(o[rt][ct][r] * inv);
    }
  }
}

extern "C" void kernel_launch(void* const* d_in, const int* in_sizes, int n_in,
                              void* d_out, int out_size, void* d_ws, size_t ws_size,
                              hipStream_t stream){
  (void)n_in; (void)out_size;
  const void* xq = d_in[0];
  const void* xk = d_in[1];
  const void* xv = d_in[2];
  const void* Wq = d_in[3];
  const void* bq = d_in[4];
  const void* Wk = d_in[5];
  const void* bk = d_in[6];
  const void* Wv = d_in[7];
  const void* bv = d_in[8];
  const void* Wo = d_in[9];
  const void* bo = d_in[10];

  // dtype from host-side size: bf16 iff input 0 is exactly NT*2 bytes.
  const long NT = (long)BS*DM;                    // 8,388,608 elements
  int f32f = 1;
  if (in_sizes && in_sizes[0] == (int)(NT*2)) f32f = 0;

  u16* base = (u16*)((char*)d_ws + 256);
  u16* Qb  = base;                                // Q (scaled), later attention O
  u16* Kbf = base + NT;
  u16* Vt  = base + 2*NT;                         // [b*16+h][64][2048], sigma-permuted
  u16* WqT = base + 3*NT;
  u16* WkT = WqT + (long)DM*DM;
  u16* WvT = WkT + (long)DM*DM;
  u16* WoT = WvT + (long)DM*DM;
  u16* Xc0 = WoT + (long)DM*DM;                   // bf16-converted activations
  u16* Xc1 = Xc0 + NT;
  u16* Xc2 = Xc1 + NT;
  size_t need_pre = 256 + (size_t)(6*NT + 4*(long)DM*DM)*2;   // ~109 MB
  bool pre = ws_size >= need_pre;

  dim3 gb(256,1,1);
  int nz = (pre && f32f) ? 7 : 4;
  prep<<<dim3(32,32,nz), gb, 0, stream>>>(Wq, Wk, Wv, Wo,
      WqT, WkT, WvT, WoT, xq, xk, xv, Xc0, Xc1, Xc2, f32f);

  if (pre){
    const void* Aq = f32f ? (const void*)Xc0 : xq;
    const void* Ak = f32f ? (const void*)Xc1 : xk;
    const void* Av = f32f ? (const void*)Xc2 : xv;
    gemm_qkv<1><<<dim3(32,8,3), gb, 0, stream>>>(Aq, Ak, Av,
        WqT, WkT, WvT, bq, bk, bv, Qb, Kbf, Vt, f32f);
  } else {
    gemm_qkv<0><<<dim3(32,8,3), gb, 0, stream>>>(xq, xk, xv,
        WqT, WkT, WvT, bq, bk, bv, Qb, Kbf, Vt, f32f);
  }

  attn5<<<dim3(1024,1,1), gb, 0, stream>>>(Qb, Kbf, Vt, Qb /* O reuses Q */);

  gemm_o<<<dim3(64,8,1), gb, 0, stream>>>(Qb, WoT, bo, d_out, f32f);
}

// Round 7
// 352.750 us; speedup vs baseline: 1.0977x; 1.0869x over previous
//
#include <hip/hip_runtime.h>

typedef unsigned short u16;
typedef unsigned int   u32;
typedef unsigned long long u64;
typedef __attribute__((ext_vector_type(8))) short bf16x8;
typedef __attribute__((ext_vector_type(4))) float f32x4;

#define S_  2048
#define DH  64
#define DM  1024
#define BS  8192
#define CS  0.18033688011112042f   // 0.125 * log2(e)

static __device__ __forceinline__ float bf2f(u16 v){ return __uint_as_float(((u32)v)<<16); }
static __device__ __forceinline__ u16 f2bf(float f){
  u32 x = __float_as_uint(f);
  return (u16)((x + 0x7fffu + ((x>>16)&1u)) >> 16);   // RNE
}
#if __has_builtin(__builtin_amdgcn_cvt_pk_bf16_f32)
static __device__ __forceinline__ u32 pk2(float x, float y){
  typedef __attribute__((ext_vector_type(2))) __bf16 bf2v;
  union { bf2v v; u32 u; } c; c.v = __builtin_amdgcn_cvt_pk_bf16_f32(x, y); return c.u;
}
#else
static __device__ __forceinline__ u32 pk2(float x, float y){
  return (u32)f2bf(x) | ((u32)f2bf(y) << 16);
}
#endif
#if __has_builtin(__builtin_amdgcn_exp2f)
#define EXP2F(x) __builtin_amdgcn_exp2f(x)
#else
#define EXP2F(x) exp2f(x)
#endif

// async global->LDS, 16B/lane; LDS dest = wave-uniform base + lane*16
static __device__ __forceinline__ void dma16(const u16* g, const u16* l){
  __builtin_amdgcn_global_load_lds(
      (const __attribute__((address_space(1))) u32*)(u64)(uintptr_t)g,
      (__attribute__((address_space(3))) u32*)(u32)(u64)(uintptr_t)l, 16, 0, 0);
}

static __device__ __forceinline__ bf16x8 lds_frag(const u16* p){
  union { bf16x8 f; uint2 u[2]; } w;
  w.u[0] = *(const uint2*)(p);
  w.u[1] = *(const uint2*)(p+4);
  return w.f;
}
// 16B-aligned fragment load (single ds_read_b128)
static __device__ __forceinline__ bf16x8 frag16v(const u16* p){
  union { bf16x8 f; uint4 u; } w;
  w.u = *(const uint4*)p;
  return w.f;
}
static __device__ __forceinline__ void stage16_bf(const u16* __restrict__ g, u16* s){
  uint4 a = *(const uint4*)g;
  uint4 b = *(const uint4*)(g+8);
  *(uint2*)(s+0)  = make_uint2(a.x,a.y);
  *(uint2*)(s+4)  = make_uint2(a.z,a.w);
  *(uint2*)(s+8)  = make_uint2(b.x,b.y);
  *(uint2*)(s+12) = make_uint2(b.z,b.w);
}
static __device__ __forceinline__ void stage16_f32(const float* __restrict__ g, u16* s){
  float4 a0 = ((const float4*)g)[0];
  float4 a1 = ((const float4*)g)[1];
  float4 a2 = ((const float4*)g)[2];
  float4 a3 = ((const float4*)g)[3];
  *(uint2*)(s+0)  = make_uint2(pk2(a0.x,a0.y), pk2(a0.z,a0.w));
  *(uint2*)(s+4)  = make_uint2(pk2(a1.x,a1.y), pk2(a1.z,a1.w));
  *(uint2*)(s+8)  = make_uint2(pk2(a2.x,a2.y), pk2(a2.z,a2.w));
  *(uint2*)(s+12) = make_uint2(pk2(a3.x,a3.y), pk2(a3.z,a3.w));
}

// prep: z=0..3 -> weight transpose (f32/bf16 -> bf16, [k][n] -> [n][k]);
//       z=4..6 -> activation f32->bf16 convert (skipped when input is bf16).
__global__ __launch_bounds__(256) void prep(
    const void* __restrict__ w0, const void* __restrict__ w1,
    const void* __restrict__ w2, const void* __restrict__ w3,
    u16* t0, u16* t1, u16* t2, u16* t3,
    const void* __restrict__ a0, const void* __restrict__ a1,
    const void* __restrict__ a2,
    u16* c0, u16* c1, u16* c2, const int f32f){
  __shared__ u16 tile[32][33];
  int z = blockIdx.z;
  int tid = threadIdx.x;
  bool f32 = f32f != 0;
  if (z < 4){
    const void* in = z==0?w0 : z==1?w1 : z==2?w2 : w3;
    u16* out = z==0?t0 : z==1?t1 : z==2?t2 : t3;
    int tx = tid & 31, ty = tid >> 5;
    int c  = blockIdx.x*32 + tx;
    int r0 = blockIdx.y*32;
    for (int i=ty;i<32;i+=8){
      long off = (long)(r0+i)*DM + c;
      tile[i][tx] = f32 ? f2bf(((const float*)in)[off]) : ((const u16*)in)[off];
    }
    __syncthreads();
    int rr = r0 + tx, cb = blockIdx.x*32;
    for (int i=ty;i<32;i+=8) out[(long)(cb+i)*DM + rr] = tile[tx][i];
  } else {
    if (!f32) return;
    const void* in = z==4?a0 : z==5?a1 : a2;
    u16* out = z==4?c0 : z==5?c1 : c2;
    long lb = (long)blockIdx.y*32 + blockIdx.x;     // 0..1023
    long base = (lb*256 + tid)*8;
    #pragma unroll
    for (int it=0; it<4; it++){
      long i = base + (long)it*2097152;
      const float4* p = (const float4*)((const float*)in + i);
      float4 x = p[0], y = p[1];
      *(uint4*)(out + i) = make_uint4(pk2(x.x,x.y), pk2(x.z,x.w), pk2(y.x,y.y), pk2(y.z,y.w));
    }
  }
}

// Fused QKV projection: z=0 -> Q (scaled by CS), z=1 -> K, z=2 -> V (written
// transposed per head with in-tile key permutation sigma:
//   n = rt*16 + q*4 + r  ->  p = 32*(rt>>1) + 8*q + 4*(rt&1) + r
// matching the attention kernel's in-register P fragment order.
// 128x128 tile, 4 waves, BK=32. ADMA=1: A is bf16, both operands DMA-staged
// with double-buffered LDS + counted vmcnt (2-phase pipeline) and a
// pair-line XOR swizzle: the 128x32 tile is viewed as 64 lines of 128B
// (2 rows each); phys_slot = log_slot ^ (line&7). global_load_lds writes
// linearly, so the SOURCE address is pre-permuted per lane and the ds_read
// applies the same XOR -> each 16-lane read phase hits every 4-bank group
// exactly twice (minimal) instead of 8x on 2 groups.
template<int ADMA>
__global__ __launch_bounds__(256) void gemm_qkv(
    const void* __restrict__ A0, const void* __restrict__ A1, const void* __restrict__ A2,
    const u16* __restrict__ W0, const u16* __restrict__ W1, const u16* __restrict__ W2,
    const void* __restrict__ bv0, const void* __restrict__ bv1, const void* __restrict__ bv2,
    u16* C0, u16* C1, u16* C2, const int f32f){
  constexpr int AST = ADMA ? 32 : 36;
  constexpr int NB  = ADMA ? 2 : 1;
  __shared__ __align__(16) u16 As[NB][128*AST];
  __shared__ __align__(16) u16 Bs[NB][128*32];
  int z = blockIdx.z;
  const void* A  = z==0?A0 : z==1?A1 : A2;
  const u16* BT  = z==0?W0 : z==1?W1 : W2;
  const void* bias = z==0?bv0 : z==1?bv1 : bv2;
  u16* C = z==0?C0 : z==1?C1 : C2;
  const bool aF32 = (!ADMA) && (f32f != 0);
  const bool bF32 = (f32f != 0);
  int tid = threadIdx.x;
  int by = blockIdx.x, bx = blockIdx.y;
  int lane = tid & 63, w = tid >> 6;
  int t = lane & 15, q = lane >> 4;
  int wr = w >> 1, wc = w & 1;
  f32x4 acc[4][4];
  #pragma unroll
  for(int i=0;i<4;i++) for(int j=0;j<4;j++) for(int k=0;k<4;k++) acc[i][j][k]=0.f;

  if constexpr (ADMA){
    // swizzled staging source: lane -> line=lane>>3, phys slot=lane&7,
    // logical slot sl = (lane&7)^line; row = 2*line + sl>>2, col16 = sl&3.
    int sl = (lane & 7) ^ (lane >> 3);
    int srow = ((lane >> 3) << 1) + (sl >> 2);
    const u16* gA = (const u16*)A + ((long)(by*128 + w*32 + srow)*DM + (sl&3)*8);
    const u16* gB = BT            + ((long)(bx*128 + w*32 + srow)*DM + (sl&3)*8);
    const int lb = w*1024;                  // wave stripe base (u16)
    // swizzled read offset for fragment row R0+t, col16 q:
    int rdo = ((t>>1)<<6) + (((((t&1)<<2) | q) ^ (t>>1)) << 3);
    // prologue: tile 0 -> buf 0
    dma16(gA,         &As[0][lb]);
    dma16(gA + 16*DM, &As[0][lb + 512]);
    dma16(gB,         &Bs[0][lb]);
    dma16(gB + 16*DM, &Bs[0][lb + 512]);
    for (int k0=0; k0<DM; k0+=32){
      int cur = (k0>>5)&1;
      if (k0+32 < DM){
        dma16(gA + k0+32,         &As[cur^1][lb]);
        dma16(gA + k0+32 + 16*DM, &As[cur^1][lb + 512]);
        dma16(gB + k0+32,         &Bs[cur^1][lb]);
        dma16(gB + k0+32 + 16*DM, &Bs[cur^1][lb + 512]);
        asm volatile("s_waitcnt vmcnt(4)" ::: "memory");   // tile k0 landed
      } else {
        asm volatile("s_waitcnt vmcnt(0)" ::: "memory");
      }
      __builtin_amdgcn_s_barrier();
      bf16x8 af[4], bfr[4];
      const u16* Ar = &As[cur][wr*2048 + rdo];
      const u16* Br = &Bs[cur][wc*2048 + rdo];
      #pragma unroll
      for (int rt=0;rt<4;rt++) af[rt]  = frag16v(Ar + rt*512);
      #pragma unroll
      for (int ct=0;ct<4;ct++) bfr[ct] = frag16v(Br + ct*512);
      #pragma unroll
      for (int rt=0;rt<4;rt++)
        #pragma unroll
        for (int ct=0;ct<4;ct++)
          acc[rt][ct] = __builtin_amdgcn_mfma_f32_16x16x32_bf16(af[rt], bfr[ct], acc[rt][ct], 0,0,0);
      __builtin_amdgcn_s_barrier();
    }
  } else {
    const u16* gB = BT + ((long)(bx*128 + w*32 + (lane>>2))*DM + (lane&3)*8);
    long aoff = (long)(by*128 + (tid>>1))*DM + (tid&1)*16;
    const u16* ArdB = &As[0][(wr*64 + t)*AST + q*8];
    const u16* BrdB = &Bs[0][(wc*64 + t)*32  + q*8];
    for (int k0=0; k0<DM; k0+=32){
      dma16(gB + k0,         &Bs[0][w*1024]);
      dma16(gB + 16*DM + k0, &Bs[0][w*1024 + 512]);
      u16* AsW = &As[0][(tid>>1)*36 + (tid&1)*16];
      if (aF32) stage16_f32((const float*)A + aoff + k0, AsW);
      else      stage16_bf ((const u16*)A  + aoff + k0, AsW);
      __syncthreads();
      bf16x8 af[4], bfr[4];
      #pragma unroll
      for (int rt=0;rt<4;rt++) af[rt]  = lds_frag(ArdB + rt*16*AST);
      #pragma unroll
      for (int ct=0;ct<4;ct++) bfr[ct] = lds_frag(BrdB + ct*16*32);
      #pragma unroll
      for (int rt=0;rt<4;rt++)
        #pragma unroll
        for (int ct=0;ct<4;ct++)
          acc[rt][ct] = __builtin_amdgcn_mfma_f32_16x16x32_bf16(af[rt], bfr[ct], acc[rt][ct], 0,0,0);
      __syncthreads();
    }
  }

  float scale = (z==0) ? CS : 1.0f;
  #pragma unroll
  for (int ct=0;ct<4;ct++){
    int col = bx*128 + wc*64 + ct*16 + t;
    float bvv = bF32 ? ((const float*)bias)[col] : bf2f(((const u16*)bias)[col]);
    #pragma unroll
    for (int rt=0;rt<4;rt++){
      int row0 = by*128 + wr*64 + rt*16 + q*4;
      if (z == 2){
        int bb = row0 >> 11, s = row0 & 2047;
        long vbase = (long)bb*2097152 + (long)col*2048
                   + (s & ~63) + ((rt>>1)<<5) + (q<<3) + ((rt&1)<<2);
        u32 lo = pk2(acc[rt][ct][0]+bvv, acc[rt][ct][1]+bvv);
        u32 hi = pk2(acc[rt][ct][2]+bvv, acc[rt][ct][3]+bvv);
        *(uint2*)(C + vbase) = make_uint2(lo,hi);
      } else {
        #pragma unroll
        for (int r=0;r<4;r++)
          C[(long)(row0+r)*DM + col] = f2bf((acc[rt][ct][r] + bvv)*scale);
      }
    }
  }
}

// Output projection: A bf16 in ws, both operands DMA-staged, double-buffered,
// same pair-line XOR swizzle as gemm_qkv<1>.
__global__ __launch_bounds__(256) void gemm_o(const u16* __restrict__ A,
    const u16* __restrict__ BT, const void* __restrict__ bias, void* __restrict__ C,
    const int f32f){
  __shared__ __align__(16) u16 As[2][128*32];
  __shared__ __align__(16) u16 Bs[2][128*32];
  const int f = f32f;
  int tid = threadIdx.x;
  int by = blockIdx.x, bx = blockIdx.y;
  int lane = tid & 63, w = tid >> 6;
  int t = lane & 15, q = lane >> 4;
  int wr = w >> 1, wc = w & 1;
  f32x4 acc[4][4];
  #pragma unroll
  for(int i=0;i<4;i++) for(int j=0;j<4;j++) for(int k=0;k<4;k++) acc[i][j][k]=0.f;

  int sl = (lane & 7) ^ (lane >> 3);
  int srow = ((lane >> 3) << 1) + (sl >> 2);
  const u16* gA = A  + ((long)(by*128 + w*32 + srow)*DM + (sl&3)*8);
  const u16* gB = BT + ((long)(bx*128 + w*32 + srow)*DM + (sl&3)*8);
  const int lb = w*1024;
  int rdo = ((t>>1)<<6) + (((((t&1)<<2) | q) ^ (t>>1)) << 3);
  // prologue: tile 0 -> buf 0
  dma16(gA,         &As[0][lb]);
  dma16(gA + 16*DM, &As[0][lb + 512]);
  dma16(gB,         &Bs[0][lb]);
  dma16(gB + 16*DM, &Bs[0][lb + 512]);
  for (int k0=0; k0<DM; k0+=32){
    int cur = (k0>>5)&1;
    if (k0+32 < DM){
      dma16(gA + k0+32,         &As[cur^1][lb]);
      dma16(gA + k0+32 + 16*DM, &As[cur^1][lb + 512]);
      dma16(gB + k0+32,         &Bs[cur^1][lb]);
      dma16(gB + k0+32 + 16*DM, &Bs[cur^1][lb + 512]);
      asm volatile("s_waitcnt vmcnt(4)" ::: "memory");
    } else {
      asm volatile("s_waitcnt vmcnt(0)" ::: "memory");
    }
    __builtin_amdgcn_s_barrier();
    bf16x8 af[4], bfr[4];
    const u16* Ar = &As[cur][wr*2048 + rdo];
    const u16* Br = &Bs[cur][wc*2048 + rdo];
    #pragma unroll
    for (int rt=0;rt<4;rt++) af[rt]  = frag16v(Ar + rt*512);
    #pragma unroll
    for (int ct=0;ct<4;ct++) bfr[ct] = frag16v(Br + ct*512);
    #pragma unroll
    for (int rt=0;rt<4;rt++)
      #pragma unroll
      for (int ct=0;ct<4;ct++)
        acc[rt][ct] = __builtin_amdgcn_mfma_f32_16x16x32_bf16(af[rt], bfr[ct], acc[rt][ct], 0,0,0);
    __builtin_amdgcn_s_barrier();
  }
  #pragma unroll
  for (int ct=0;ct<4;ct++){
    int col = bx*128 + wc*64 + ct*16 + t;
    float bvv = f ? ((const float*)bias)[col] : bf2f(((const u16*)bias)[col]);
    #pragma unroll
    for (int rt=0;rt<4;rt++){
      int row0 = by*128 + wr*64 + rt*16 + q*4;
      #pragma unroll
      for (int r=0;r<4;r++){
        long idx = (long)(row0+r)*DM + col;
        float v = acc[rt][ct][r] + bvv;
        if (f) ((float*)C)[idx] = v;
        else   ((u16*)C)[idx]  = f2bf(v);
      }
    }
  }
}

// Flash attention v5 (proven R2 schedule; no online max; Q pre-scaled by CS).
// Swapped QK^T: mfma(K, Q) puts P[qrow=t][key=16c+4q+r] lane-local; V is
// stored (by gemm_qkv) with the sigma key-permutation so PV A-fragments are
// built entirely in-register (cvt_pk only): NO P LDS round-trip. Row sums
// via a constant ones-column B-fragment MFMA (o4). K/V double-buffered in
// stride-64 LDS via global_load_lds with XOR-pre-swizzled source. Two
// barriers/iter; prefetch issued before vmcnt(4) (race-free: the
// end-of-iteration barrier orders all reads of the target buffer before any
// wave's next-iteration prefetch). LDS=32KB -> 4 blocks/CU (grid 1024).
__global__ __launch_bounds__(256,4) void attn5(const u16* __restrict__ Q,
    const u16* __restrict__ Kb, const u16* __restrict__ Vt, u16* __restrict__ O){
  __shared__ __align__(16) u16 Ks[2][4096];   // [buf][64 s-rows][64 d], swizzled
  __shared__ __align__(16) u16 Vs[2][4096];   // [buf][64 dh-rows][64 kpos], swizzled
  int tid = threadIdx.x;
  int bid = blockIdx.x;
  int qt = bid >> 6;
  int s6 = bid & 63;
  int bh = (s6 & 7)*8 + (s6 >> 3);   // all 16 qt-blocks of a bh share bid%8 -> same XCD
  int b = bh >> 4, h = bh & 15;
  int lane = tid & 63, w = tid >> 6;
  int t = lane & 15, q = lane >> 4;

  // Q fragments (B-operand): col = qrow = t (+rt*16), k = d = ks*32 + q*8 ..
  const u16* Qbase = Q + ((long)(b*S_ + qt*128 + w*32 + t)*DM + h*DH + q*8);
  bf16x8 qf[2][2];
  qf[0][0] = frag16v(Qbase);
  qf[0][1] = frag16v(Qbase + 32);
  qf[1][0] = frag16v(Qbase + 16*DM);
  qf[1][1] = frag16v(Qbase + 16*DM + 32);

  // DMA chunk mapping: chunk c = tid; row = c>>3, 16B-slot = c&7,
  // global source slot pre-swizzled by row&7 so linear LDS + XOR read works.
  int r0 = tid >> 3;
  int cb = ((tid & 7) * 16) ^ ((r0 & 7) << 4);
  const char* gK = (const char*)Kb + (((long)(b*S_ + r0)*DM + h*DH) << 1) + cb;
  const char* gV = (const char*)Vt + ((((long)bh << 17) + ((long)r0 << 11)) << 1) + cb;
  const long gK1 = ((long)32*DM) << 1;     // +32 s-rows
  const long gV1 = ((long)32*S_) << 1;     // +32 dh-rows
  const int ld0 = w*512, ld1 = 2048 + w*512;   // wave-uniform LDS bases (u16)

  f32x4 o[2][4];
  #pragma unroll
  for (int i=0;i<2;i++) for (int j=0;j<4;j++) for (int k=0;k<4;k++) o[i][j][k]=0.f;
  f32x4 o4[2];
  #pragma unroll
  for (int i=0;i<2;i++) for (int k=0;k<4;k++) o4[i][k]=0.f;

  // ones B-fragment: column 0 all-ones -> o4 row-sums
  union { bf16x8 f; u32 u[4]; } vone;
  { u32 ovv = (t==0) ? 0x3F803F80u : 0u;
    vone.u[0]=ovv; vone.u[1]=ovv; vone.u[2]=ovv; vone.u[3]=ovv; }

  const int xorv = (t & 7) << 4;   // read-side byte XOR (row&7 == t&7 for all frags)

  // prologue: stage tile 0 into buf 0
  dma16((const u16*)(gK),       &Ks[0][ld0]);
  dma16((const u16*)(gK + gK1), &Ks[0][ld1]);
  dma16((const u16*)(gV),       &Vs[0][ld0]);
  dma16((const u16*)(gV + gV1), &Vs[0][ld1]);

  for (int kt=0; kt<32; kt++){
    int cur = kt & 1;
    if (kt < 31){
      long ko = ((long)(kt+1)*64*DM) << 1;   // K advances 64 s-rows
      long vo = (long)(kt+1) << 7;           // V advances 64 key-positions (128 B)
      dma16((const u16*)(gK + ko),       &Ks[cur^1][ld0]);
      dma16((const u16*)(gK + ko + gK1), &Ks[cur^1][ld1]);
      dma16((const u16*)(gV + vo),       &Vs[cur^1][ld0]);
      dma16((const u16*)(gV + vo + gV1), &Vs[cur^1][ld1]);
      asm volatile("s_waitcnt vmcnt(4)" ::: "memory");   // tile kt ready, kt+1 in flight
    } else {
      asm volatile("s_waitcnt vmcnt(0)" ::: "memory");
    }
    __builtin_amdgcn_s_barrier();

    const u16* Kc = Ks[cur];
    const u16* Vc = Vs[cur];

    // QK^T swapped: mfma(K, Q) -> lane (t,q) holds P[qrow=t][key=16c+4q+r]
    f32x4 sacc[2][4];
    #pragma unroll
    for (int i=0;i<2;i++) for (int j=0;j<4;j++) for (int k=0;k<4;k++) sacc[i][j][k]=0.f;
    #pragma unroll
    for (int ks=0; ks<2; ks++){
      int off = ((ks*64 + q*16) ^ xorv) >> 1;
      bf16x8 k0 = frag16v(Kc + (t     )*64 + off);
      bf16x8 k1 = frag16v(Kc + (16 + t)*64 + off);
      bf16x8 k2 = frag16v(Kc + (32 + t)*64 + off);
      bf16x8 k3 = frag16v(Kc + (48 + t)*64 + off);
      __builtin_amdgcn_s_setprio(1);
      #pragma unroll
      for (int rt=0; rt<2; rt++){
        sacc[rt][0] = __builtin_amdgcn_mfma_f32_16x16x32_bf16(k0, qf[rt][ks], sacc[rt][0],0,0,0);
        sacc[rt][1] = __builtin_amdgcn_mfma_f32_16x16x32_bf16(k1, qf[rt][ks], sacc[rt][1],0,0,0);
        sacc[rt][2] = __builtin_amdgcn_mfma_f32_16x16x32_bf16(k2, qf[rt][ks], sacc[rt][2],0,0,0);
        sacc[rt][3] = __builtin_amdgcn_mfma_f32_16x16x32_bf16(k3, qf[rt][ks], sacc[rt][3],0,0,0);
      }
      __builtin_amdgcn_s_setprio(0);
    }

    // softmax (no max-sub) + in-register P->A-fragment pack:
    // af[rt][ks] element e = exp2(sacc[rt][2ks + (e>>2)][e&3])
    union { bf16x8 f; u32 u[4]; } af[2][2];
    #pragma unroll
    for (int rt=0; rt<2; rt++){
      float ev[4][4];
      #pragma unroll
      for (int c=0; c<4; c++)
        #pragma unroll
        for (int r=0; r<4; r++) ev[c][r] = EXP2F(sacc[rt][c][r]);
      #pragma unroll
      for (int ks=0; ks<2; ks++){
        af[rt][ks].u[0] = pk2(ev[2*ks  ][0], ev[2*ks  ][1]);
        af[rt][ks].u[1] = pk2(ev[2*ks  ][2], ev[2*ks  ][3]);
        af[rt][ks].u[2] = pk2(ev[2*ks+1][0], ev[2*ks+1][1]);
        af[rt][ks].u[3] = pk2(ev[2*ks+1][2], ev[2*ks+1][3]);
      }
    }

    // PV: O += P * V ; V columns are sigma-permuted to match af's key order.
    #pragma unroll
    for (int ks=0; ks<2; ks++){
      int off = ((ks*64 + q*16) ^ xorv) >> 1;
      bf16x8 v0 = frag16v(Vc + (t     )*64 + off);
      bf16x8 v1 = frag16v(Vc + (16 + t)*64 + off);
      bf16x8 v2 = frag16v(Vc + (32 + t)*64 + off);
      bf16x8 v3 = frag16v(Vc + (48 + t)*64 + off);
      __builtin_amdgcn_s_setprio(1);
      #pragma unroll
      for (int rt=0; rt<2; rt++){
        o[rt][0] = __builtin_amdgcn_mfma_f32_16x16x32_bf16(af[rt][ks].f, v0, o[rt][0],0,0,0);
        o[rt][1] = __builtin_amdgcn_mfma_f32_16x16x32_bf16(af[rt][ks].f, v1, o[rt][1],0,0,0);
        o[rt][2] = __builtin_amdgcn_mfma_f32_16x16x32_bf16(af[rt][ks].f, v2, o[rt][2],0,0,0);
        o[rt][3] = __builtin_amdgcn_mfma_f32_16x16x32_bf16(af[rt][ks].f, v3, o[rt][3],0,0,0);
        o4[rt]   = __builtin_amdgcn_mfma_f32_16x16x32_bf16(af[rt][ks].f, vone.f, o4[rt],0,0,0);
      }
      __builtin_amdgcn_s_setprio(0);
    }
    __builtin_amdgcn_s_barrier();
  }

  // epilogue: l = row sum (held at lanes t==0 of same q), broadcast, normalize
  #pragma unroll
  for (int rt=0; rt<2; rt++){
    #pragma unroll
    for (int r=0; r<4; r++){
      float l = __shfl(o4[rt][r], lane & 48);
      float inv = 1.f / l;
      int row = qt*128 + w*32 + rt*16 + q*4 + r;
      #pragma unroll
      for (int ct=0; ct<4; ct++)
        O[(long)(b*S_ + row)*DM + h*DH + ct*16 + t] = f2bf(o[rt][ct][r] * inv);
    }
  }
}

extern "C" void kernel_launch(void* const* d_in, const int* in_sizes, int n_in,
                              void* d_out, int out_size, void* d_ws, size_t ws_size,
                              hipStream_t stream){
  (void)n_in; (void)out_size;
  const void* xq = d_in[0];
  const void* xk = d_in[1];
  const void* xv = d_in[2];
  const void* Wq = d_in[3];
  const void* bq = d_in[4];
  const void* Wk = d_in[5];
  const void* bk = d_in[6];
  const void* Wv = d_in[7];
  const void* bv = d_in[8];
  const void* Wo = d_in[9];
  const void* bo = d_in[10];

  // dtype from host-side size: bf16 iff input 0 is exactly NT*2 bytes.
  const long NT = (long)BS*DM;                    // 8,388,608 elements
  int f32f = 1;
  if (in_sizes && in_sizes[0] == (int)(NT*2)) f32f = 0;

  u16* base = (u16*)((char*)d_ws + 256);
  u16* Qb  = base;                                // Q (scaled), later attention O
  u16* Kbf = base + NT;
  u16* Vt  = base + 2*NT;                         // [b*16+h][64][2048], sigma-permuted
  u16* WqT = base + 3*NT;
  u16* WkT = WqT + (long)DM*DM;
  u16* WvT = WkT + (long)DM*DM;
  u16* WoT = WvT + (long)DM*DM;
  u16* Xc0 = WoT + (long)DM*DM;                   // bf16-converted activations
  u16* Xc1 = Xc0 + NT;
  u16* Xc2 = Xc1 + NT;
  size_t need_pre = 256 + (size_t)(6*NT + 4*(long)DM*DM)*2;   // ~109 MB
  bool pre = ws_size >= need_pre;

  dim3 gb(256,1,1);
  int nz = (pre && f32f) ? 7 : 4;
  prep<<<dim3(32,32,nz), gb, 0, stream>>>(Wq, Wk, Wv, Wo,
      WqT, WkT, WvT, WoT, xq, xk, xv, Xc0, Xc1, Xc2, f32f);

  if (pre){
    const void* Aq = f32f ? (const void*)Xc0 : xq;
    const void* Ak = f32f ? (const void*)Xc1 : xk;
    const void* Av = f32f ? (const void*)Xc2 : xv;
    gemm_qkv<1><<<dim3(64,8,3), gb, 0, stream>>>(Aq, Ak, Av,
        WqT, WkT, WvT, bq, bk, bv, Qb, Kbf, Vt, f32f);
  } else {
    gemm_qkv<0><<<dim3(64,8,3), gb, 0, stream>>>(xq, xk, xv,
        WqT, WkT, WvT, bq, bk, bv, Qb, Kbf, Vt, f32f);
  }

  attn5<<<dim3(1024,1,1), gb, 0, stream>>>(Qb, Kbf, Vt, Qb /* O reuses Q */);

  gemm_o<<<dim3(64,8,1), gb, 0, stream>>>(Qb, WoT, bo, d_out, f32f);
}